// Round 1
// baseline (539.118 us; speedup 1.0000x reference)
//
#include <hip/hip_runtime.h>

#define N_NODES 50000
#define C_ 128
#define E_ 10
#define K0_ 640                 // scalar path: S, S2, VV, S2S, SVV
#define K1_ 512                 // vector path: Vm, S*Vm, S2*Vm, VV*Vm
#define TILE_ 16
#define TILES_PER_E ((N_NODES + TILE_ - 1) / TILE_)   // 3125

// workspace layout (bytes)
#define W0_BYTES (E_ * K0_ * C_ * 4)                  // 3,276,800
#define W1_BYTES (E_ * K1_ * C_ * 4)                  // 2,621,440
#define CNT_OFF  (W0_BYTES + W1_BYTES)                // 5,898,240
#define LIST_OFF (CNT_OFF + 256)

__global__ void zero_cnt_kernel(int* __restrict__ cnt) {
    if (threadIdx.x < E_) cnt[threadIdx.x] = 0;
}

// grid: E_*(K0_+K1_) blocks of 128 threads. Each block builds one row of
// W0eff/W1eff: fold tp2/tp3/INV3/norms into coef rows, merge duplicate base
// segments, then multiply by lin_w and NORM_C.
__global__ void prep_weights_kernel(
    const float* __restrict__ tp2, const float* __restrict__ tp3,
    const float* __restrict__ c00, const float* __restrict__ c10, const float* __restrict__ c20,
    const float* __restrict__ c01, const float* __restrict__ c11, const float* __restrict__ c21,
    const float* __restrict__ lin0, const float* __restrict__ lin1,
    float* __restrict__ W0, float* __restrict__ W1)
{
    const int b = blockIdx.x;
    const int e = b / (K0_ + K1_);
    const int r = b % (K0_ + K1_);
    const int which = (r >= K0_) ? 1 : 0;
    const int k = which ? (r - K0_) : r;
    const int seg = k >> 7;
    const int c = k & 127;
    const int tid = threadIdx.x;    // 128

    const float i128 = 0.08838834764831845f;   // 1/sqrt(128)
    const float i256 = 0.0625f;                // 1/sqrt(256)
    const float i512 = 0.04419417382415922f;   // 1/sqrt(512)
    const float I3   = 0.5773502691896258f;    // 1/sqrt(3)
    const float I9   = I3 * I3;

    const float t2_0 = tp2[0*C_+c], t2_1 = tp2[1*C_+c], t2_2 = tp2[2*C_+c], t2_3 = tp2[3*C_+c];
    const float t3_0 = tp3[0*C_+c], t3_1 = tp3[1*C_+c], t3_2 = tp3[2*C_+c];
    const float t3_3 = tp3[3*C_+c], t3_4 = tp3[4*C_+c], t3_5 = tp3[5*C_+c];
    const float t3_6 = tp3[6*C_+c], t3_7 = tp3[7*C_+c];

    __shared__ float row[C_];
    const int jj = tid;
    float val;
    if (!which) {
        const float* C0 = c00 + e * C_   * C_;
        const float* C1 = c10 + e * 2*C_ * C_;
        const float* C2 = c20 + e * 4*C_ * C_;
        switch (seg) {
        case 0: val = i128 * C0[c*C_ + jj]; break;                                  // base S
        case 1: val = t2_0 * i256 * C1[c*C_ + jj]; break;                           // base S2 (m0a)
        case 2: val = t2_3 * I3 * i256 * C1[(C_+c)*C_ + jj]; break;                 // base VV (m0b)
        case 3: val = t3_0 * t2_0 * i512 * C2[c*C_ + jj]; break;                    // base S2S (q0a)
        default: val = i512 * ( t3_3*t2_1*I9 * C2[(C_  +c)*C_ + jj]                 // base SVV (q0b)
                              + t3_5*t2_2*I9 * C2[(2*C_+c)*C_ + jj]                 //          (q0c)
                              + t3_6*t2_3*I3 * C2[(3*C_+c)*C_ + jj] ); break;       //          (q0d)
        }
    } else {
        const float* C0 = c01 + e * C_   * C_;
        const float* C1 = c11 + e * 2*C_ * C_;
        const float* C2 = c21 + e * 4*C_ * C_;
        switch (seg) {
        case 0: val = i128 * C0[c*C_ + jj]; break;                                  // base Vm
        case 1: val = I3 * i256 * ( t2_1 * C1[c*C_ + jj]                            // base S*Vm (m1a)
                                  + t2_2 * C1[(C_+c)*C_ + jj] ); break;             //           (m1b)
        case 2: val = i512 * ( t3_1*t2_0*I3 * C2[c*C_ + jj]                         // base S2*Vm (q1a)
                             + t3_2*t2_1*I9 * C2[(C_  +c)*C_ + jj]                  //            (q1b)
                             + t3_4*t2_2*I9 * C2[(2*C_+c)*C_ + jj] ); break;        //            (q1c)
        default: val = i512 * t3_7*t2_3*I9 * C2[(3*C_+c)*C_ + jj]; break;           // base VV*Vm (q1d)
        }
    }
    row[jj] = val;
    __syncthreads();

    const float* lin = which ? lin1 : lin0;
    float acc = 0.f;
#pragma unroll 8
    for (int x = 0; x < C_; ++x) acc += row[x] * lin[x*C_ + tid];
    const float NC = 0.08838834764831845f;   // final 1/sqrt(C)
    if (!which) W0[(e*K0_ + k)*C_ + tid] = acc * NC;
    else        W1[(e*K1_ + k)*C_ + tid] = acc * NC;
}

// Bucket nodes by element via one-hot argmax. Order within a bucket is
// nondeterministic but outputs are per-node independent -> deterministic out.
__global__ void bucket_kernel(const float* __restrict__ attrs,
                              int* __restrict__ cnt, int* __restrict__ lists)
{
    __shared__ int lcnt[E_];
    __shared__ int lbase[E_];
    const int n = blockIdx.x * 256 + threadIdx.x;
    if (threadIdx.x < E_) lcnt[threadIdx.x] = 0;
    __syncthreads();
    int e = 0, my = 0;
    if (n < N_NODES) {
        const float* a = attrs + (size_t)n * E_;
#pragma unroll
        for (int i = 0; i < E_; ++i) if (a[i] > 0.5f) e = i;
        my = atomicAdd(&lcnt[e], 1);
    }
    __syncthreads();
    if (threadIdx.x < E_) lbase[threadIdx.x] = atomicAdd(&cnt[threadIdx.x], lcnt[threadIdx.x]);
    __syncthreads();
    if (n < N_NODES) lists[e*N_NODES + lbase[e] + my] = n;
}

// Main: one block = 16 same-element nodes. Stage {S,V0,V1,V2} and
// {S2,VV,S*VV,S2*S} per (node,channel) in LDS; thread = 2 nodes x 4 columns.
__global__ __launch_bounds__(256) void main_kernel(
    const float* __restrict__ feats, const float* __restrict__ sc,
    const int* __restrict__ cnt, const int* __restrict__ lists,
    const float* __restrict__ W0, const float* __restrict__ W1,
    float* __restrict__ out)
{
    const int bx = blockIdx.x;
    const int e = bx / TILES_PER_E;
    const int tile = bx % TILES_PER_E;
    const int count = cnt[e];
    const int start = tile * TILE_;
    if (start >= count) return;
    const int nvalid = min(TILE_, count - start);

    __shared__ float4 svA[TILE_][C_];   // S, V0, V1, V2
    __shared__ float4 svB[TILE_][C_];   // S2, VV, S*VV, S2*S
    __shared__ int nodes[TILE_];

    const int tid = threadIdx.x;
    if (tid < TILE_) nodes[tid] = (tid < nvalid) ? lists[e*N_NODES + start + tid] : -1;
    __syncthreads();

    {   // load + derive phase: thread = (node slot, 8-channel group)
        const int i  = tid >> 4;
        const int cg = tid & 15;
        const int n  = nodes[i];
        float s8[8], v24[24];
        if (n >= 0) {
            const float* f = feats + (size_t)n * 512;
            *(float4*)&s8[0] = *(const float4*)(f + (cg << 3));
            *(float4*)&s8[4] = *(const float4*)(f + (cg << 3) + 4);
#pragma unroll
            for (int q = 0; q < 6; ++q)
                *(float4*)&v24[4*q] = *(const float4*)(f + C_ + cg*24 + 4*q);
        } else {
#pragma unroll
            for (int q = 0; q < 8; ++q)  s8[q] = 0.f;
#pragma unroll
            for (int q = 0; q < 24; ++q) v24[q] = 0.f;
        }
#pragma unroll
        for (int jj = 0; jj < 8; ++jj) {
            const int c = (cg << 3) + jj;
            const float S = s8[jj];
            const float V0 = v24[3*jj], V1 = v24[3*jj+1], V2 = v24[3*jj+2];
            const float S2 = S * S;
            const float VV = V0*V0 + V1*V1 + V2*V2;
            svA[i][c] = make_float4(S, V0, V1, V2);
            svB[i][c] = make_float4(S2, VV, S*VV, S2*S);
        }
    }
    __syncthreads();

    const int jlane = tid & 31;     // cols jlane, +32, +64, +96
    const int ig    = tid >> 5;     // nodes 2*ig, 2*ig+1
    const int i0 = 2*ig, i1 = 2*ig + 1;

    const float* __restrict__ W0e = W0 + (size_t)e * K0_ * C_;
    const float* __restrict__ W1e = W1 + (size_t)e * K1_ * C_;

    float acc0[2][4];
    float acc1[2][4][3];
#pragma unroll
    for (int i = 0; i < 2; ++i)
#pragma unroll
        for (int jc = 0; jc < 4; ++jc) {
            acc0[i][jc] = 0.f;
#pragma unroll
            for (int m = 0; m < 3; ++m) acc1[i][jc][m] = 0.f;
        }

    for (int c = 0; c < C_; ++c) {
        const float4 a0 = svA[i0][c], b0 = svB[i0][c];
        const float4 a1 = svA[i1][c], b1 = svB[i1][c];
        const float* w0p = W0e + c*C_ + jlane;
        const float* w1p = W1e + c*C_ + jlane;
#pragma unroll
        for (int jc = 0; jc < 4; ++jc) {
            const int jo = jc * 32;
            const float w00 = w0p[jo];
            const float w01 = w0p[1*C_*C_ + jo];
            const float w02 = w0p[2*C_*C_ + jo];
            const float w03 = w0p[3*C_*C_ + jo];
            const float w04 = w0p[4*C_*C_ + jo];
            acc0[0][jc] += a0.x*w00 + b0.x*w01 + b0.y*w02 + b0.w*w03 + b0.z*w04;
            acc0[1][jc] += a1.x*w00 + b1.x*w01 + b1.y*w02 + b1.w*w03 + b1.z*w04;

            const float w10 = w1p[jo];
            const float w11 = w1p[1*C_*C_ + jo];
            const float w12 = w1p[2*C_*C_ + jo];
            const float w13 = w1p[3*C_*C_ + jo];
            const float t0 = w10 + a0.x*w11 + b0.x*w12 + b0.y*w13;
            acc1[0][jc][0] += a0.y*t0; acc1[0][jc][1] += a0.z*t0; acc1[0][jc][2] += a0.w*t0;
            const float t1 = w10 + a1.x*w11 + b1.x*w12 + b1.y*w13;
            acc1[1][jc][0] += a1.y*t1; acc1[1][jc][1] += a1.z*t1; acc1[1][jc][2] += a1.w*t1;
        }
    }

#pragma unroll
    for (int i = 0; i < 2; ++i) {
        const int n = nodes[2*ig + i];
        if (n < 0) continue;
        const size_t base = (size_t)n * 512;
#pragma unroll
        for (int jc = 0; jc < 4; ++jc) {
            const int j = jlane + jc*32;
            out[base + j] = acc0[i][jc] + sc[base + j];
#pragma unroll
            for (int m = 0; m < 3; ++m)
                out[base + C_ + 3*j + m] = acc1[i][jc][m] + sc[base + C_ + 3*j + m];
        }
    }
}

extern "C" void kernel_launch(void* const* d_in, const int* in_sizes, int n_in,
                              void* d_out, int out_size, void* d_ws, size_t ws_size,
                              hipStream_t stream) {
    const float* feats = (const float*)d_in[0];
    const float* attrs = (const float*)d_in[1];
    const float* sc    = (const float*)d_in[2];
    const float* tp2   = (const float*)d_in[3];
    const float* tp3   = (const float*)d_in[4];
    const float* c00   = (const float*)d_in[5];   // coef0_w0 (E,C,C)
    const float* c01   = (const float*)d_in[6];   // coef0_w1 (E,C,C)
    const float* c10   = (const float*)d_in[7];   // coef1_w0 (E,2C,C)
    const float* c11   = (const float*)d_in[8];   // coef1_w1 (E,2C,C)
    const float* c20   = (const float*)d_in[9];   // coef2_w0 (E,4C,C)
    const float* c21   = (const float*)d_in[10];  // coef2_w1 (E,4C,C)
    const float* lin0  = (const float*)d_in[11];
    const float* lin1  = (const float*)d_in[12];
    float* out = (float*)d_out;

    char* ws = (char*)d_ws;
    float* W0  = (float*)(ws);
    float* W1  = (float*)(ws + W0_BYTES);
    int* cnt   = (int*)(ws + CNT_OFF);
    int* lists = (int*)(ws + LIST_OFF);

    hipLaunchKernelGGL(zero_cnt_kernel, dim3(1), dim3(64), 0, stream, cnt);
    hipLaunchKernelGGL(prep_weights_kernel, dim3(E_*(K0_+K1_)), dim3(128), 0, stream,
                       tp2, tp3, c00, c10, c20, c01, c11, c21, lin0, lin1, W0, W1);
    hipLaunchKernelGGL(bucket_kernel, dim3((N_NODES + 255)/256), dim3(256), 0, stream,
                       attrs, cnt, lists);
    hipLaunchKernelGGL(main_kernel, dim3(E_*TILES_PER_E), dim3(256), 0, stream,
                       feats, sc, cnt, lists, W0, W1, out);
}

// Round 2
// 322.707 us; speedup vs baseline: 1.6706x; 1.6706x over previous
//
#include <hip/hip_runtime.h>

typedef unsigned short u16;
typedef __attribute__((ext_vector_type(8))) short short8;
typedef __attribute__((ext_vector_type(4))) float f32x4;

#define N_NODES 50000
#define C_ 128
#define E_ 10
#define NT_ 16
#define NBLK_MAIN 3200
#define K0_ 640
#define K1_ 512

// workspace layout (bytes)
#define W0T_BYTES (E_ * 128 * K0_ * 2)           // 1,638,400 bf16
#define W1T_BYTES (E_ * 128 * K1_ * 2)           // 1,310,720 bf16
#define CNT_OFF   (W0T_BYTES + W1T_BYTES)
#define STARTS_OFF (CNT_OFF + 64)
#define LIST_OFF  (STARTS_OFF + 64)

__device__ __forceinline__ float bf2f(u16 h){ union{unsigned u; float f;} v; v.u = ((unsigned)h)<<16; return v.f; }
__device__ __forceinline__ u16 f2bf(float f){ union{unsigned u; float f;} v; v.f = f; unsigned u = v.u; u += 0x7FFFu + ((u>>16)&1u); return (u16)(u>>16); }

__global__ void zero_cnt_kernel(int* __restrict__ cnt) {
    if (threadIdx.x < E_) cnt[threadIdx.x] = 0;
}

// One block per (e, k-row). Fold tp2/tp3/INV3/path-norms into coef rows, merge
// duplicate base segments, multiply by lin_w * NORM_C, store TRANSPOSED bf16:
// W0T[e][col][k] (k<640), W1T[e][col][k] (k<512).
__global__ void prep_weights_kernel(
    const float* __restrict__ tp2, const float* __restrict__ tp3,
    const float* __restrict__ c00, const float* __restrict__ c10, const float* __restrict__ c20,
    const float* __restrict__ c01, const float* __restrict__ c11, const float* __restrict__ c21,
    const float* __restrict__ lin0, const float* __restrict__ lin1,
    u16* __restrict__ W0T, u16* __restrict__ W1T)
{
    const int b = blockIdx.x;
    const int e = b / (K0_ + K1_);
    const int r = b % (K0_ + K1_);
    const int which = (r >= K0_) ? 1 : 0;
    const int k = which ? (r - K0_) : r;
    const int seg = k >> 7;
    const int c = k & 127;
    const int tid = threadIdx.x;    // 128

    const float i128 = 0.08838834764831845f;
    const float i256 = 0.0625f;
    const float i512 = 0.04419417382415922f;
    const float I3   = 0.5773502691896258f;
    const float I9   = I3 * I3;

    const float t2_0 = tp2[0*C_+c], t2_1 = tp2[1*C_+c], t2_2 = tp2[2*C_+c], t2_3 = tp2[3*C_+c];
    const float t3_0 = tp3[0*C_+c], t3_1 = tp3[1*C_+c], t3_2 = tp3[2*C_+c];
    const float t3_3 = tp3[3*C_+c], t3_4 = tp3[4*C_+c], t3_5 = tp3[5*C_+c];
    const float t3_6 = tp3[6*C_+c], t3_7 = tp3[7*C_+c];

    __shared__ float row[C_];
    const int jj = tid;
    float val;
    if (!which) {
        const float* C0 = c00 + e * C_   * C_;
        const float* C1 = c10 + e * 2*C_ * C_;
        const float* C2 = c20 + e * 4*C_ * C_;
        switch (seg) {
        case 0: val = i128 * C0[c*C_ + jj]; break;                                  // base S
        case 1: val = t2_0 * i256 * C1[c*C_ + jj]; break;                           // base S2
        case 2: val = t2_3 * I3 * i256 * C1[(C_+c)*C_ + jj]; break;                 // base VV
        case 3: val = t3_0 * t2_0 * i512 * C2[c*C_ + jj]; break;                    // base S3
        default: val = i512 * ( t3_3*t2_1*I9 * C2[(C_  +c)*C_ + jj]                 // base S*VV
                              + t3_5*t2_2*I9 * C2[(2*C_+c)*C_ + jj]
                              + t3_6*t2_3*I3 * C2[(3*C_+c)*C_ + jj] ); break;
        }
    } else {
        const float* C0 = c01 + e * C_   * C_;
        const float* C1 = c11 + e * 2*C_ * C_;
        const float* C2 = c21 + e * 4*C_ * C_;
        switch (seg) {
        case 0: val = i128 * C0[c*C_ + jj]; break;                                  // base Vm
        case 1: val = I3 * i256 * ( t2_1 * C1[c*C_ + jj]                            // base S*Vm
                                  + t2_2 * C1[(C_+c)*C_ + jj] ); break;
        case 2: val = i512 * ( t3_1*t2_0*I3 * C2[c*C_ + jj]                         // base S2*Vm
                             + t3_2*t2_1*I9 * C2[(C_  +c)*C_ + jj]
                             + t3_4*t2_2*I9 * C2[(2*C_+c)*C_ + jj] ); break;
        default: val = i512 * t3_7*t2_3*I9 * C2[(3*C_+c)*C_ + jj]; break;           // base VV*Vm
        }
    }
    row[jj] = val;
    __syncthreads();

    const float* lin = which ? lin1 : lin0;
    float acc = 0.f;
#pragma unroll 8
    for (int x = 0; x < C_; ++x) acc += row[x] * lin[x*C_ + tid];
    const float NC = 0.08838834764831845f;
    if (!which) W0T[((size_t)(e*128 + tid))*K0_ + k] = f2bf(acc * NC);
    else        W1T[((size_t)(e*128 + tid))*K1_ + k] = f2bf(acc * NC);
}

__global__ void bucket_kernel(const float* __restrict__ attrs,
                              int* __restrict__ cnt, int* __restrict__ lists)
{
    __shared__ int lcnt[E_];
    __shared__ int lbase[E_];
    const int n = blockIdx.x * 256 + threadIdx.x;
    if (threadIdx.x < E_) lcnt[threadIdx.x] = 0;
    __syncthreads();
    int e = 0, my = 0;
    if (n < N_NODES) {
        const float* a = attrs + (size_t)n * E_;
#pragma unroll
        for (int i = 0; i < E_; ++i) if (a[i] > 0.5f) e = i;
        my = atomicAdd(&lcnt[e], 1);
    }
    __syncthreads();
    if (threadIdx.x < E_) lbase[threadIdx.x] = atomicAdd(&cnt[threadIdx.x], lcnt[threadIdx.x]);
    __syncthreads();
    if (n < N_NODES) lists[e*N_NODES + lbase[e] + my] = n;
}

__global__ void plan_kernel(const int* __restrict__ cnt, int* __restrict__ starts) {
    if (threadIdx.x == 0) {
        int acc = 0;
        for (int e = 0; e < E_; ++e) { starts[e] = acc; acc += (cnt[e] + NT_ - 1) / NT_; }
        starts[E_] = acc;
    }
}

// Main: 16 same-element nodes per block, 512 threads = 8 waves.
// Phase 1: compute all 17 feature panels in fp32 from global feats, scatter
//   bf16 into fragment-linear LDS A (68 slots x 64 lanes x 8 elems).
// Phase 2: pure MFMA K-loop; B fragments loaded 8B/lane from bf16 W^T (L2).
// Slot map: scalar p in 0..4 -> slot p*4+ks; vector q in 0..3, comp m ->
//   slot 20 + q*12 + m*4 + ks.  Fragment (lane,elem)->k: k = ks*32 +
//   (elem>>2)*16 + (lane>>4)*4 + (elem&3)  [same bijection for A and B, so
//   any HW k-permutation cancels; C/D layout is the m89-verified one].
__global__ __launch_bounds__(512, 4) void main_kernel(
    const float* __restrict__ feats, const float* __restrict__ sc,
    const int* __restrict__ cnt, const int* __restrict__ starts,
    const int* __restrict__ lists,
    const u16* __restrict__ W0T, const u16* __restrict__ W1T,
    float* __restrict__ out)
{
    __shared__ __align__(16) u16 Afull[68 * 64 * 8];   // 69,632 B
    __shared__ int nodes_s[NT_];
    __shared__ int hdr[2];

    const int tid = threadIdx.x;
    const int bx = blockIdx.x;
    if (tid == 0) {
        if (bx >= starts[E_]) { hdr[0] = -1; hdr[1] = 0; }
        else {
            int e = 0;
            while (e < E_ - 1 && bx >= starts[e+1]) ++e;
            hdr[0] = e; hdr[1] = bx - starts[e];
        }
    }
    __syncthreads();
    const int e = hdr[0];
    if (e < 0) return;
    const int tile = hdr[1];
    const int nvalid = min(NT_, cnt[e] - tile * NT_);

    if (tid < NT_) nodes_s[tid] = (tid < nvalid) ? lists[e*N_NODES + tile*NT_ + tid] : -1;
    __syncthreads();

    // ---------- phase 1: features -> LDS fragments ----------
    {
        const int node = tid >> 5;          // 0..15
        const int cg   = tid & 31;          // 4 channels per thread
        const int n = nodes_s[node];
        float4 sv  = make_float4(0.f,0.f,0.f,0.f);
        float4 va  = sv, vb = sv, vc = sv;
        if (n >= 0) {
            const float* f = feats + (size_t)n * 512;
            sv = *(const float4*)(f + cg*4);
            va = *(const float4*)(f + 128 + cg*12);
            vb = *(const float4*)(f + 128 + cg*12 + 4);
            vc = *(const float4*)(f + 128 + cg*12 + 8);
        }
        float Sa[4]  = {sv.x, sv.y, sv.z, sv.w};
        float Va[12] = {va.x,va.y,va.z,va.w, vb.x,vb.y,vb.z,vb.w, vc.x,vc.y,vc.z,vc.w};

        u16 fsS[5][4];        // scalar panels: S, S2, VV, S3, S*VV
        u16 fsV[4][3][4];     // vector panels: q in {1,S,S2,VV} x comp m
#pragma unroll
        for (int i = 0; i < 4; ++i) {
            const float S  = Sa[i];
            const float V0 = Va[3*i], V1 = Va[3*i+1], V2 = Va[3*i+2];
            const float S2 = S * S;
            const float VV = V0*V0 + V1*V1 + V2*V2;
            fsS[0][i] = f2bf(S);
            fsS[1][i] = f2bf(S2);
            fsS[2][i] = f2bf(VV);
            fsS[3][i] = f2bf(S2 * S);
            fsS[4][i] = f2bf(S * VV);
            const float Vm[3] = {V0, V1, V2};
#pragma unroll
            for (int m = 0; m < 3; ++m) {
                fsV[0][m][i] = f2bf(Vm[m]);
                fsV[1][m][i] = f2bf(S  * Vm[m]);
                fsV[2][m][i] = f2bf(S2 * Vm[m]);
                fsV[3][m][i] = f2bf(VV * Vm[m]);
            }
        }
        // c = cg*4 + i: lane = node + 16*(cg&3); ks = cg>>3; elem base = ((cg>>2)&1)*4
        const int lane  = node + 16 * (cg & 3);
        const int ks    = cg >> 3;
        const int ebase = ((cg >> 2) & 1) * 4;
        u16* bp = &Afull[lane*8 + ebase];
#pragma unroll
        for (int p = 0; p < 5; ++p)
            *(ushort4*)&bp[(p*4 + ks) * 512] = *(ushort4*)fsS[p];
#pragma unroll
        for (int q = 0; q < 4; ++q)
#pragma unroll
            for (int m = 0; m < 3; ++m)
                *(ushort4*)&bp[(20 + q*12 + m*4 + ks) * 512] = *(ushort4*)fsV[q][m];
    }
    __syncthreads();

    // ---------- phase 2: MFMA ----------
    const int w = tid >> 6, l = tid & 63;
    const int lcol = l & 15, g = l >> 4;
    const int col = w*16 + lcol;
    const u16* Wp0 = W0T + ((size_t)(e*128 + col)) * K0_;
    const u16* Wp1 = W1T + ((size_t)(e*128 + col)) * K1_;

    f32x4 accS = {0.f, 0.f, 0.f, 0.f};
    f32x4 accV[3];
#pragma unroll
    for (int m = 0; m < 3; ++m) accV[m] = accS;

#pragma unroll
    for (int p = 0; p < 5; ++p) {
#pragma unroll
        for (int ks = 0; ks < 4; ++ks) {
            const u16* wp = Wp0 + p*128 + ks*32 + 4*g;
            union { uint2 u2[2]; short8 v; } b;
            b.u2[0] = *(const uint2*)(wp);
            b.u2[1] = *(const uint2*)(wp + 16);
            const short8 a = *(const short8*)&Afull[((p*4 + ks)*64 + l) * 8];
            accS = __builtin_amdgcn_mfma_f32_16x16x32_bf16(a, b.v, accS, 0, 0, 0);
        }
    }
#pragma unroll
    for (int q = 0; q < 4; ++q) {
#pragma unroll
        for (int ks = 0; ks < 4; ++ks) {
            const u16* wp = Wp1 + q*128 + ks*32 + 4*g;
            union { uint2 u2[2]; short8 v; } b;
            b.u2[0] = *(const uint2*)(wp);
            b.u2[1] = *(const uint2*)(wp + 16);
#pragma unroll
            for (int m = 0; m < 3; ++m) {
                const short8 a = *(const short8*)&Afull[((20 + q*12 + m*4 + ks)*64 + l) * 8];
                accV[m] = __builtin_amdgcn_mfma_f32_16x16x32_bf16(a, b.v, accV[m], 0, 0, 0);
            }
        }
    }

    // ---------- epilogue: D row = 4*g + r, col = l&15 (m89-verified) ----------
#pragma unroll
    for (int r = 0; r < 4; ++r) {
        const int node = 4*g + r;
        const int n = nodes_s[node];
        if (n >= 0) {
            const size_t base = (size_t)n*512 + col;
            out[base] = accS[r] + sc[base];
        }
    }
#pragma unroll
    for (int m = 0; m < 3; ++m)
#pragma unroll
        for (int r = 0; r < 4; ++r) {
            const int node = 4*g + r;
            const int n = nodes_s[node];
            if (n >= 0) {
                const size_t base = (size_t)n*512 + 128 + 3*(size_t)col + m;
                out[base] = accV[m][r] + sc[base];
            }
        }
}

extern "C" void kernel_launch(void* const* d_in, const int* in_sizes, int n_in,
                              void* d_out, int out_size, void* d_ws, size_t ws_size,
                              hipStream_t stream) {
    const float* feats = (const float*)d_in[0];
    const float* attrs = (const float*)d_in[1];
    const float* sc    = (const float*)d_in[2];
    const float* tp2   = (const float*)d_in[3];
    const float* tp3   = (const float*)d_in[4];
    const float* c00   = (const float*)d_in[5];
    const float* c01   = (const float*)d_in[6];
    const float* c10   = (const float*)d_in[7];
    const float* c11   = (const float*)d_in[8];
    const float* c20   = (const float*)d_in[9];
    const float* c21   = (const float*)d_in[10];
    const float* lin0  = (const float*)d_in[11];
    const float* lin1  = (const float*)d_in[12];
    float* out = (float*)d_out;

    char* ws = (char*)d_ws;
    u16* W0T   = (u16*)(ws);
    u16* W1T   = (u16*)(ws + W0T_BYTES);
    int* cnt   = (int*)(ws + CNT_OFF);
    int* starts= (int*)(ws + STARTS_OFF);
    int* lists = (int*)(ws + LIST_OFF);

    hipLaunchKernelGGL(zero_cnt_kernel, dim3(1), dim3(64), 0, stream, cnt);
    hipLaunchKernelGGL(prep_weights_kernel, dim3(E_*(K0_+K1_)), dim3(128), 0, stream,
                       tp2, tp3, c00, c10, c20, c01, c11, c21, lin0, lin1, W0T, W1T);
    hipLaunchKernelGGL(bucket_kernel, dim3((N_NODES + 255)/256), dim3(256), 0, stream,
                       attrs, cnt, lists);
    hipLaunchKernelGGL(plan_kernel, dim3(1), dim3(64), 0, stream, cnt, starts);
    hipLaunchKernelGGL(main_kernel, dim3(NBLK_MAIN), dim3(512), 0, stream,
                       feats, sc, cnt, starts, lists, W0T, W1T, out);
}

// Round 3
// 129.053 us; speedup vs baseline: 4.1775x; 2.5006x over previous
//
#include <hip/hip_runtime.h>

typedef unsigned short u16;
typedef __attribute__((ext_vector_type(8))) short short8;
typedef __attribute__((ext_vector_type(4))) float f32x4;

#define N_NODES 50000
#define C_ 128
#define E_ 10
#define NT_ 16
#define NBLK_MAIN 3200
#define K0_ 640
#define K1_ 512

// fragment-linear weight buffers:
// WF0: [E][8 waves][20 slots][64 lanes][8 elems] bf16
// WF1: [E][8 waves][16 slots][64 lanes][8 elems] bf16
#define WF0_BYTES (E_ * 8 * 20 * 512 * 2)        // 1,638,400
#define WF1_BYTES (E_ * 8 * 16 * 512 * 2)        // 1,310,720
#define CNT_OFF   (WF0_BYTES + WF1_BYTES)
#define STARTS_OFF (CNT_OFF + 64)
#define LIST_OFF  (STARTS_OFF + 64)

__device__ __forceinline__ u16 f2bf(float f){ union{unsigned u; float f;} v; v.f = f; unsigned u = v.u; u += 0x7FFFu + ((u>>16)&1u); return (u16)(u>>16); }

__global__ void zero_cnt_kernel(int* __restrict__ cnt) {
    if (threadIdx.x < E_) cnt[threadIdx.x] = 0;
}

// One block per (e, k-row). Fold tp2/tp3/INV3/path-norms into coef rows, merge
// duplicate base segments, multiply by lin_w * NORM_C, store bf16 in MFMA
// B-fragment-linear order. Fragment bijection (same as A side):
//   channel c = ks*32 + eh*16 + g*4 + el ; lane = lcol + 16*g ; elem = eh*4+el
__global__ void prep_weights_kernel(
    const float* __restrict__ tp2, const float* __restrict__ tp3,
    const float* __restrict__ c00, const float* __restrict__ c10, const float* __restrict__ c20,
    const float* __restrict__ c01, const float* __restrict__ c11, const float* __restrict__ c21,
    const float* __restrict__ lin0, const float* __restrict__ lin1,
    u16* __restrict__ WF0, u16* __restrict__ WF1)
{
    const int b = blockIdx.x;
    const int e = b / (K0_ + K1_);
    const int r = b % (K0_ + K1_);
    const int which = (r >= K0_) ? 1 : 0;
    const int k = which ? (r - K0_) : r;
    const int seg = k >> 7;
    const int c = k & 127;
    const int tid = threadIdx.x;    // 128 = output col

    const float i128 = 0.08838834764831845f;
    const float i256 = 0.0625f;
    const float i512 = 0.04419417382415922f;
    const float I3   = 0.5773502691896258f;
    const float I9   = I3 * I3;

    const float t2_0 = tp2[0*C_+c], t2_1 = tp2[1*C_+c], t2_2 = tp2[2*C_+c], t2_3 = tp2[3*C_+c];
    const float t3_0 = tp3[0*C_+c], t3_1 = tp3[1*C_+c], t3_2 = tp3[2*C_+c];
    const float t3_3 = tp3[3*C_+c], t3_4 = tp3[4*C_+c], t3_5 = tp3[5*C_+c];
    const float t3_6 = tp3[6*C_+c], t3_7 = tp3[7*C_+c];

    __shared__ float row[C_];
    const int jj = tid;
    float val;
    if (!which) {
        const float* C0 = c00 + e * C_   * C_;
        const float* C1 = c10 + e * 2*C_ * C_;
        const float* C2 = c20 + e * 4*C_ * C_;
        switch (seg) {
        case 0: val = i128 * C0[c*C_ + jj]; break;                                  // base S
        case 1: val = t2_0 * i256 * C1[c*C_ + jj]; break;                           // base S2
        case 2: val = t2_3 * I3 * i256 * C1[(C_+c)*C_ + jj]; break;                 // base VV
        case 3: val = t3_0 * t2_0 * i512 * C2[c*C_ + jj]; break;                    // base S3
        default: val = i512 * ( t3_3*t2_1*I9 * C2[(C_  +c)*C_ + jj]                 // base S*VV
                              + t3_5*t2_2*I9 * C2[(2*C_+c)*C_ + jj]
                              + t3_6*t2_3*I3 * C2[(3*C_+c)*C_ + jj] ); break;
        }
    } else {
        const float* C0 = c01 + e * C_   * C_;
        const float* C1 = c11 + e * 2*C_ * C_;
        const float* C2 = c21 + e * 4*C_ * C_;
        switch (seg) {
        case 0: val = i128 * C0[c*C_ + jj]; break;                                  // base Vm
        case 1: val = I3 * i256 * ( t2_1 * C1[c*C_ + jj]                            // base S*Vm
                                  + t2_2 * C1[(C_+c)*C_ + jj] ); break;
        case 2: val = i512 * ( t3_1*t2_0*I3 * C2[c*C_ + jj]                         // base S2*Vm
                             + t3_2*t2_1*I9 * C2[(C_  +c)*C_ + jj]
                             + t3_4*t2_2*I9 * C2[(2*C_+c)*C_ + jj] ); break;
        default: val = i512 * t3_7*t2_3*I9 * C2[(3*C_+c)*C_ + jj]; break;           // base VV*Vm
        }
    }
    row[jj] = val;
    __syncthreads();

    const float* lin = which ? lin1 : lin0;
    float acc = 0.f;
#pragma unroll 8
    for (int x = 0; x < C_; ++x) acc += row[x] * lin[x*C_ + tid];
    const float NC = 0.08838834764831845f;
    const u16 wv = f2bf(acc * NC);

    // fragment-linear store
    const int col = tid;
    const int w_ = col >> 4, lcol = col & 15;
    const int ks = (c >> 5), r2 = c & 31;
    const int eh = r2 >> 4, g = (r2 >> 2) & 3, el = r2 & 3;
    const int elem = eh*4 + el;
    const int lane = lcol + 16*g;
    if (!which) {
        const int slot = seg*4 + ks;         // p in 0..4 -> 0..19
        WF0[(((size_t)(e*8 + w_))*20 + slot)*512 + lane*8 + elem] = wv;
    } else {
        const int slot = seg*4 + ks;         // q in 0..3 -> 0..15
        WF1[(((size_t)(e*8 + w_))*16 + slot)*512 + lane*8 + elem] = wv;
    }
}

__global__ void bucket_kernel(const float* __restrict__ attrs,
                              int* __restrict__ cnt, int* __restrict__ lists)
{
    __shared__ int lcnt[E_];
    __shared__ int lbase[E_];
    const int n = blockIdx.x * 256 + threadIdx.x;
    if (threadIdx.x < E_) lcnt[threadIdx.x] = 0;
    __syncthreads();
    int e = 0, my = 0;
    if (n < N_NODES) {
        const float* a = attrs + (size_t)n * E_;
#pragma unroll
        for (int i = 0; i < E_; ++i) if (a[i] > 0.5f) e = i;
        my = atomicAdd(&lcnt[e], 1);
    }
    __syncthreads();
    if (threadIdx.x < E_) lbase[threadIdx.x] = atomicAdd(&cnt[threadIdx.x], lcnt[threadIdx.x]);
    __syncthreads();
    if (n < N_NODES) lists[e*N_NODES + lbase[e] + my] = n;
}

__global__ void plan_kernel(const int* __restrict__ cnt, int* __restrict__ starts) {
    if (threadIdx.x == 0) {
        int acc = 0;
        for (int e = 0; e < E_; ++e) { starts[e] = acc; acc += (cnt[e] + NT_ - 1) / NT_; }
        starts[E_] = acc;
    }
}

// Main: 16 same-element nodes per block, 512 threads = 8 waves.
// A-LDS: 68 slots x 64 chunk x 16B; chunk for logical lane L of slot s is
// L ^ ((s&3)<<1) (same involution on write & read; spreads phase-1 write banks).
// Epilogue: accs -> LDS (float, stride 516) -> coalesced float4 sc/out.
__global__ __launch_bounds__(512, 4) void main_kernel(
    const float* __restrict__ feats, const float* __restrict__ sc,
    const int* __restrict__ cnt, const int* __restrict__ starts,
    const int* __restrict__ lists,
    const u16* __restrict__ WF0, const u16* __restrict__ WF1,
    float* __restrict__ out)
{
    __shared__ __align__(16) u16 Afull[68 * 512];   // 69,632 B (reused as float out-stage)
    __shared__ int nodes_s[NT_];
    __shared__ int hdr[2];

    const int tid = threadIdx.x;
    const int bx = blockIdx.x;
    if (tid == 0) {
        if (bx >= starts[E_]) { hdr[0] = -1; hdr[1] = 0; }
        else {
            int e = 0;
            while (e < E_ - 1 && bx >= starts[e+1]) ++e;
            hdr[0] = e; hdr[1] = bx - starts[e];
        }
    }
    __syncthreads();
    const int e = hdr[0];
    if (e < 0) return;
    const int tile = hdr[1];
    const int nvalid = min(NT_, cnt[e] - tile * NT_);

    if (tid < NT_) nodes_s[tid] = (tid < nvalid) ? lists[e*N_NODES + tile*NT_ + tid] : -1;
    __syncthreads();

    // ---------- phase 1: features -> LDS A fragments ----------
    {
        const int node = tid >> 5;          // 0..15
        const int cg   = tid & 31;          // 4 channels per thread
        const int n = nodes_s[node];
        float4 sv  = make_float4(0.f,0.f,0.f,0.f);
        float4 va  = sv, vb = sv, vc = sv;
        if (n >= 0) {
            const float* f = feats + (size_t)n * 512;
            sv = *(const float4*)(f + cg*4);
            va = *(const float4*)(f + 128 + cg*12);
            vb = *(const float4*)(f + 128 + cg*12 + 4);
            vc = *(const float4*)(f + 128 + cg*12 + 8);
        }
        float Sa[4]  = {sv.x, sv.y, sv.z, sv.w};
        float Va[12] = {va.x,va.y,va.z,va.w, vb.x,vb.y,vb.z,vb.w, vc.x,vc.y,vc.z,vc.w};

        u16 fsS[5][4];
        u16 fsV[4][3][4];
#pragma unroll
        for (int i = 0; i < 4; ++i) {
            const float S  = Sa[i];
            const float V0 = Va[3*i], V1 = Va[3*i+1], V2 = Va[3*i+2];
            const float S2 = S * S;
            const float VV = V0*V0 + V1*V1 + V2*V2;
            fsS[0][i] = f2bf(S);
            fsS[1][i] = f2bf(S2);
            fsS[2][i] = f2bf(VV);
            fsS[3][i] = f2bf(S2 * S);
            fsS[4][i] = f2bf(S * VV);
            const float Vm[3] = {V0, V1, V2};
#pragma unroll
            for (int m = 0; m < 3; ++m) {
                fsV[0][m][i] = f2bf(Vm[m]);
                fsV[1][m][i] = f2bf(S  * Vm[m]);
                fsV[2][m][i] = f2bf(S2 * Vm[m]);
                fsV[3][m][i] = f2bf(VV * Vm[m]);
            }
        }
        const int lane  = node + 16 * (cg & 3);
        const int ks    = cg >> 3;
        const int ebase = ((cg >> 2) & 1) * 4;
        const int lanep = lane ^ (ks << 1);           // XOR swizzle (involution)
        u16* bp = &Afull[lanep*8 + ebase];
#pragma unroll
        for (int p = 0; p < 5; ++p)
            *(ushort4*)&bp[(p*4 + ks) * 512] = *(ushort4*)fsS[p];
#pragma unroll
        for (int q = 0; q < 4; ++q)
#pragma unroll
            for (int m = 0; m < 3; ++m)
                *(ushort4*)&bp[(20 + q*12 + m*4 + ks) * 512] = *(ushort4*)fsV[q][m];
    }
    __syncthreads();

    // ---------- phase 2: MFMA, coalesced fragment-linear B ----------
    const int w = tid >> 6, l = tid & 63;
    const int lcol = l & 15, g = l >> 4;
    const int col = w*16 + lcol;
    const u16* WB0 = WF0 + ((size_t)(e*8 + w)) * 20 * 512;
    const u16* WB1 = WF1 + ((size_t)(e*8 + w)) * 16 * 512;

    f32x4 accS = {0.f, 0.f, 0.f, 0.f};
    f32x4 accV[3];
#pragma unroll
    for (int m = 0; m < 3; ++m) accV[m] = accS;

#pragma unroll
    for (int p = 0; p < 5; ++p) {
#pragma unroll
        for (int ks = 0; ks < 4; ++ks) {
            const int slot = p*4 + ks;
            const short8 b = *(const short8*)(WB0 + (size_t)slot*512 + l*8);
            const short8 a = *(const short8*)&Afull[(size_t)slot*512 + (l ^ (ks<<1))*8];
            accS = __builtin_amdgcn_mfma_f32_16x16x32_bf16(a, b, accS, 0, 0, 0);
        }
    }
#pragma unroll
    for (int q = 0; q < 4; ++q) {
#pragma unroll
        for (int ks = 0; ks < 4; ++ks) {
            const short8 b = *(const short8*)(WB1 + (size_t)(q*4 + ks)*512 + l*8);
            const int lp = (l ^ (ks<<1)) * 8;
#pragma unroll
            for (int m = 0; m < 3; ++m) {
                const short8 a = *(const short8*)&Afull[(size_t)(20 + q*12 + m*4 + ks)*512 + lp];
                accV[m] = __builtin_amdgcn_mfma_f32_16x16x32_bf16(a, b, accV[m], 0, 0, 0);
            }
        }
    }

    // ---------- phase 3: stage results in LDS, then coalesced epilogue ----------
    __syncthreads();                       // everyone done reading A
    float* OutB = (float*)Afull;           // 16 x 516 floats = 33,024 B
#pragma unroll
    for (int r = 0; r < 4; ++r) {
        const int node = 4*g + r;
        OutB[node*516 + col] = accS[r];
#pragma unroll
        for (int m = 0; m < 3; ++m)
            OutB[node*516 + 128 + 3*col + m] = accV[m][r];
    }
    __syncthreads();

    {
        const int node = tid >> 5;         // 0..15
        const int ch   = tid & 31;
        const int n = nodes_s[node];
        if (n >= 0) {
            const size_t gb = (size_t)n * 512;
#pragma unroll
            for (int j = 0; j < 4; ++j) {
                const int fo = ch*4 + 128*j;
                const float4 vres = *(const float4*)&OutB[node*516 + fo];
                const float4 s4   = *(const float4*)(sc + gb + fo);
                float4 o; o.x = vres.x + s4.x; o.y = vres.y + s4.y;
                o.z = vres.z + s4.z; o.w = vres.w + s4.w;
                *(float4*)(out + gb + fo) = o;
            }
        }
    }
}

extern "C" void kernel_launch(void* const* d_in, const int* in_sizes, int n_in,
                              void* d_out, int out_size, void* d_ws, size_t ws_size,
                              hipStream_t stream) {
    const float* feats = (const float*)d_in[0];
    const float* attrs = (const float*)d_in[1];
    const float* sc    = (const float*)d_in[2];
    const float* tp2   = (const float*)d_in[3];
    const float* tp3   = (const float*)d_in[4];
    const float* c00   = (const float*)d_in[5];
    const float* c01   = (const float*)d_in[6];
    const float* c10   = (const float*)d_in[7];
    const float* c11   = (const float*)d_in[8];
    const float* c20   = (const float*)d_in[9];
    const float* c21   = (const float*)d_in[10];
    const float* lin0  = (const float*)d_in[11];
    const float* lin1  = (const float*)d_in[12];
    float* out = (float*)d_out;

    char* ws = (char*)d_ws;
    u16* WF0   = (u16*)(ws);
    u16* WF1   = (u16*)(ws + WF0_BYTES);
    int* cnt   = (int*)(ws + CNT_OFF);
    int* starts= (int*)(ws + STARTS_OFF);
    int* lists = (int*)(ws + LIST_OFF);

    hipLaunchKernelGGL(zero_cnt_kernel, dim3(1), dim3(64), 0, stream, cnt);
    hipLaunchKernelGGL(prep_weights_kernel, dim3(E_*(K0_+K1_)), dim3(128), 0, stream,
                       tp2, tp3, c00, c10, c20, c01, c11, c21, lin0, lin1, WF0, WF1);
    hipLaunchKernelGGL(bucket_kernel, dim3((N_NODES + 255)/256), dim3(256), 0, stream,
                       attrs, cnt, lists);
    hipLaunchKernelGGL(plan_kernel, dim3(1), dim3(64), 0, stream, cnt, starts);
    hipLaunchKernelGGL(main_kernel, dim3(NBLK_MAIN), dim3(512), 0, stream,
                       feats, sc, cnt, starts, lists, WF0, WF1, out);
}

// Round 4
// 118.199 us; speedup vs baseline: 4.5611x; 1.0918x over previous
//
#include <hip/hip_runtime.h>

typedef unsigned short u16;
typedef __attribute__((ext_vector_type(8))) short short8;
typedef __attribute__((ext_vector_type(4))) float f32x4;

#define N_NODES 50000
#define C_ 128
#define E_ 10
#define NT_ 16
#define NBLK_MAIN 3200
#define K0_ 640
#define K1_ 512

// fragment-linear weight buffers:
// WF0: [E][8 waves][20 slots][64 lanes][8 elems] bf16
// WF1: [E][8 waves][16 slots][64 lanes][8 elems] bf16
#define WF0_BYTES (E_ * 8 * 20 * 512 * 2)        // 1,638,400
#define WF1_BYTES (E_ * 8 * 16 * 512 * 2)        // 1,310,720
#define CNT_OFF   (WF0_BYTES + WF1_BYTES)
#define LIST_OFF  (CNT_OFF + 64)

__device__ __forceinline__ u16 f2bf(float f){ union{unsigned u; float f;} v; v.f = f; unsigned u = v.u; u += 0x7FFFu + ((u>>16)&1u); return (u16)(u>>16); }

__global__ void zero_cnt_kernel(int* __restrict__ cnt) {
    if (threadIdx.x < E_) cnt[threadIdx.x] = 0;
}

// MFMA-based weight prep: grid = E_*9 blocks of 256 threads (4 waves).
// Block (e,kb) computes a 128x128 tile of the fused weight matrix:
//   Wout[k][col] = sum_jj R[k][jj] * lin[jj][col] * NORM_C
// where R rows fold tp2/tp3/INV3/path-norms into the coef rows (duplicate
// base segments merged). kb 0..4 -> scalar path (lin0), 5..8 -> vector (lin1).
// Output stored bf16 fragment-linear (same (lane,elem)->k bijection as main).
__global__ __launch_bounds__(256) void prep_weights_kernel(
    const float* __restrict__ tp2, const float* __restrict__ tp3,
    const float* __restrict__ c00, const float* __restrict__ c10, const float* __restrict__ c20,
    const float* __restrict__ c01, const float* __restrict__ c11, const float* __restrict__ c21,
    const float* __restrict__ lin0, const float* __restrict__ lin1,
    u16* __restrict__ WF0, u16* __restrict__ WF1)
{
    const int b = blockIdx.x;
    const int e = b / 9, kb = b % 9;
    const int which = (kb >= 5) ? 1 : 0;
    const int seg = which ? kb - 5 : kb;
    const float* __restrict__ lin = which ? lin1 : lin0;

    __shared__ u16 R[128 * 136];     // [k][jj], stride 136 (pad: 2-way banks)
    __shared__ u16 LT[128 * 132];    // lin^T * NC, [col][jj], stride 132

    const int tid = threadIdx.x;     // 256
    const float NC = 0.08838834764831845f;

    // stage LT = bf16(lin * NC) transposed
    for (int t = tid; t < 128 * 32; t += 256) {
        const int jj = t >> 5, c4 = (t & 31) << 2;
        const float4 v = *(const float4*)(lin + jj * 128 + c4);
        LT[(c4 + 0) * 132 + jj] = f2bf(v.x * NC);
        LT[(c4 + 1) * 132 + jj] = f2bf(v.y * NC);
        LT[(c4 + 2) * 132 + jj] = f2bf(v.z * NC);
        LT[(c4 + 3) * 132 + jj] = f2bf(v.w * NC);
    }

    // build R: thread = (c = tid>>1, jj-half)
    {
        const int c = tid >> 1, jh = (tid & 1) * 64;
        const float i128 = 0.08838834764831845f;
        const float i256 = 0.0625f;
        const float i512 = 0.04419417382415922f;
        const float I3   = 0.5773502691896258f;
        const float I9   = I3 * I3;
        const float t2_0 = tp2[0*C_+c], t2_1 = tp2[1*C_+c], t2_2 = tp2[2*C_+c], t2_3 = tp2[3*C_+c];
        const float t3_0 = tp3[0*C_+c], t3_1 = tp3[1*C_+c], t3_2 = tp3[2*C_+c];
        const float t3_3 = tp3[3*C_+c], t3_4 = tp3[4*C_+c], t3_5 = tp3[5*C_+c];
        const float t3_6 = tp3[6*C_+c], t3_7 = tp3[7*C_+c];

        const float* P0; const float* P1 = nullptr; const float* P2 = nullptr;
        float a0 = 0.f, a1 = 0.f, a2 = 0.f;
        if (!which) {
            const float* C0 = c00 + (size_t)e * C_   * C_;
            const float* C1 = c10 + (size_t)e * 2*C_ * C_;
            const float* C2 = c20 + (size_t)e * 4*C_ * C_;
            switch (seg) {
            case 0: P0 = C0 + c*C_;          a0 = i128; break;
            case 1: P0 = C1 + c*C_;          a0 = t2_0 * i256; break;
            case 2: P0 = C1 + (C_+c)*C_;     a0 = t2_3 * I3 * i256; break;
            case 3: P0 = C2 + c*C_;          a0 = t3_0 * t2_0 * i512; break;
            default:
                P0 = C2 + (C_+c)*C_;         a0 = t3_3 * t2_1 * I9 * i512;
                P1 = C2 + (2*C_+c)*C_;       a1 = t3_5 * t2_2 * I9 * i512;
                P2 = C2 + (3*C_+c)*C_;       a2 = t3_6 * t2_3 * I3 * i512; break;
            }
        } else {
            const float* C0 = c01 + (size_t)e * C_   * C_;
            const float* C1 = c11 + (size_t)e * 2*C_ * C_;
            const float* C2 = c21 + (size_t)e * 4*C_ * C_;
            switch (seg) {
            case 0: P0 = C0 + c*C_;          a0 = i128; break;
            case 1: P0 = C1 + c*C_;          a0 = t2_1 * I3 * i256;
                    P1 = C1 + (C_+c)*C_;     a1 = t2_2 * I3 * i256; break;
            case 2: P0 = C2 + c*C_;          a0 = t3_1 * t2_0 * I3 * i512;
                    P1 = C2 + (C_+c)*C_;     a1 = t3_2 * t2_1 * I9 * i512;
                    P2 = C2 + (2*C_+c)*C_;   a2 = t3_4 * t2_2 * I9 * i512; break;
            default: P0 = C2 + (3*C_+c)*C_;  a0 = t3_7 * t2_3 * I9 * i512; break;
            }
        }
        for (int j4 = 0; j4 < 64; j4 += 4) {
            const int jj = jh + j4;
            const float4 v = *(const float4*)(P0 + jj);
            float r0 = a0*v.x, r1 = a0*v.y, r2 = a0*v.z, r3 = a0*v.w;
            if (P1) {
                const float4 u = *(const float4*)(P1 + jj);
                r0 += a1*u.x; r1 += a1*u.y; r2 += a1*u.z; r3 += a1*u.w;
            }
            if (P2) {
                const float4 u = *(const float4*)(P2 + jj);
                r0 += a2*u.x; r1 += a2*u.y; r2 += a2*u.z; r3 += a2*u.w;
            }
            ushort4 st; st.x = f2bf(r0); st.y = f2bf(r1); st.z = f2bf(r2); st.w = f2bf(r3);
            *(ushort4*)&R[c * 136 + jj] = st;
        }
    }
    __syncthreads();

    // GEMM: wave wv handles k-strips {wv, wv+4}; 8 col-tiles each.
    const int wv = tid >> 6, l = tid & 63;
    const int lcol = l & 15, gD = l >> 4;
    f32x4 acc[2][8];
#pragma unroll
    for (int s = 0; s < 2; ++s)
#pragma unroll
        for (int t = 0; t < 8; ++t) acc[s][t] = (f32x4){0.f, 0.f, 0.f, 0.f};

#pragma unroll
    for (int ks2 = 0; ks2 < 4; ++ks2) {
        const int jj0 = ks2 * 32 + gD * 4;
        short8 bf[8];
#pragma unroll
        for (int t = 0; t < 8; ++t) {
            const int colB = t * 16 + lcol;
            union { unsigned long long q[2]; short8 v; } u;
            u.q[0] = *(const unsigned long long*)&LT[colB * 132 + jj0];
            u.q[1] = *(const unsigned long long*)&LT[colB * 132 + jj0 + 16];
            bf[t] = u.v;
        }
#pragma unroll
        for (int s = 0; s < 2; ++s) {
            const int krow = (wv + s * 4) * 16 + lcol;
            union { unsigned long long q[2]; short8 v; } ua;
            ua.q[0] = *(const unsigned long long*)&R[krow * 136 + jj0];
            ua.q[1] = *(const unsigned long long*)&R[krow * 136 + jj0 + 16];
#pragma unroll
            for (int t = 0; t < 8; ++t)
                acc[s][t] = __builtin_amdgcn_mfma_f32_16x16x32_bf16(ua.v, bf[t], acc[s][t], 0, 0, 0);
        }
    }

    // store fragment-linear
#pragma unroll
    for (int s = 0; s < 2; ++s) {
#pragma unroll
        for (int r = 0; r < 4; ++r) {
            const int k = (wv + s * 4) * 16 + 4 * gD + r;
            const int ks = k >> 5, r2 = k & 31;
            const int eh = r2 >> 4, g2 = (r2 >> 2) & 3, el = r2 & 3;
            const int elem = eh * 4 + el;
            const int lanef = lcol + 16 * g2;
            const int slot = seg * 4 + ks;
#pragma unroll
            for (int t = 0; t < 8; ++t) {
                const u16 wvl = f2bf(acc[s][t][r]);
                if (!which) WF0[(((size_t)(e*8 + t))*20 + slot)*512 + lanef*8 + elem] = wvl;
                else        WF1[(((size_t)(e*8 + t))*16 + slot)*512 + lanef*8 + elem] = wvl;
            }
        }
    }
}

__global__ void bucket_kernel(const float* __restrict__ attrs,
                              int* __restrict__ cnt, int* __restrict__ lists)
{
    __shared__ int lcnt[E_];
    __shared__ int lbase[E_];
    const int n = blockIdx.x * 256 + threadIdx.x;
    if (threadIdx.x < E_) lcnt[threadIdx.x] = 0;
    __syncthreads();
    int e = 0, my = 0;
    if (n < N_NODES) {
        const float* a = attrs + (size_t)n * E_;
#pragma unroll
        for (int i = 0; i < E_; ++i) if (a[i] > 0.5f) e = i;
        my = atomicAdd(&lcnt[e], 1);
    }
    __syncthreads();
    if (threadIdx.x < E_) lbase[threadIdx.x] = atomicAdd(&cnt[threadIdx.x], lcnt[threadIdx.x]);
    __syncthreads();
    if (n < N_NODES) lists[e*N_NODES + lbase[e] + my] = n;
}

// Main: 16 same-element nodes/block, 512 threads = 8 waves, 3 barriers.
__global__ __launch_bounds__(512, 4) void main_kernel(
    const float* __restrict__ feats, const float* __restrict__ sc,
    const int* __restrict__ cnt, const int* __restrict__ lists,
    const u16* __restrict__ WF0, const u16* __restrict__ WF1,
    float* __restrict__ out)
{
    __shared__ __align__(16) u16 Afull[68 * 512];   // 69,632 B (reused as out-stage)

    const int tid = threadIdx.x;
    const int bx = blockIdx.x;

    // uniform tile search (no LDS, no barrier)
    int e = -1, tile = 0, accT = 0;
#pragma unroll
    for (int i = 0; i < E_; ++i) {
        const int ci = cnt[i];
        const int t = (ci + NT_ - 1) >> 4;
        if (e < 0 && bx < accT + t) { e = i; tile = bx - accT; }
        accT += t;
    }
    if (e < 0) return;
    const int nvalid = min(NT_, cnt[e] - tile * NT_);

    const int node = tid >> 5;          // 0..15 (phase-1 & epilogue role)
    const int ch   = tid & 31;
    const int n = (node < nvalid) ? lists[e*N_NODES + tile*NT_ + node] : -1;

    // ---------- phase 1: features -> LDS A fragments ----------
    {
        const int cg = ch;              // 4 channels per thread
        float4 sv  = make_float4(0.f,0.f,0.f,0.f);
        float4 va  = sv, vb = sv, vc = sv;
        if (n >= 0) {
            const float* f = feats + (size_t)n * 512;
            sv = *(const float4*)(f + cg*4);
            va = *(const float4*)(f + 128 + cg*12);
            vb = *(const float4*)(f + 128 + cg*12 + 4);
            vc = *(const float4*)(f + 128 + cg*12 + 8);
        }
        float Sa[4]  = {sv.x, sv.y, sv.z, sv.w};
        float Va[12] = {va.x,va.y,va.z,va.w, vb.x,vb.y,vb.z,vb.w, vc.x,vc.y,vc.z,vc.w};

        u16 fsS[5][4];
        u16 fsV[4][3][4];
#pragma unroll
        for (int i = 0; i < 4; ++i) {
            const float S  = Sa[i];
            const float V0 = Va[3*i], V1 = Va[3*i+1], V2 = Va[3*i+2];
            const float S2 = S * S;
            const float VV = V0*V0 + V1*V1 + V2*V2;
            fsS[0][i] = f2bf(S);
            fsS[1][i] = f2bf(S2);
            fsS[2][i] = f2bf(VV);
            fsS[3][i] = f2bf(S2 * S);
            fsS[4][i] = f2bf(S * VV);
            const float Vm[3] = {V0, V1, V2};
#pragma unroll
            for (int m = 0; m < 3; ++m) {
                fsV[0][m][i] = f2bf(Vm[m]);
                fsV[1][m][i] = f2bf(S  * Vm[m]);
                fsV[2][m][i] = f2bf(S2 * Vm[m]);
                fsV[3][m][i] = f2bf(VV * Vm[m]);
            }
        }
        const int lane  = node + 16 * (cg & 3);
        const int ks    = cg >> 3;
        const int ebase = ((cg >> 2) & 1) * 4;
        const int lanep = lane ^ (ks << 1);           // XOR swizzle (involution)
        u16* bp = &Afull[lanep*8 + ebase];
#pragma unroll
        for (int p = 0; p < 5; ++p)
            *(ushort4*)&bp[(p*4 + ks) * 512] = *(ushort4*)fsS[p];
#pragma unroll
        for (int q = 0; q < 4; ++q)
#pragma unroll
            for (int m = 0; m < 3; ++m)
                *(ushort4*)&bp[(20 + q*12 + m*4 + ks) * 512] = *(ushort4*)fsV[q][m];
    }
    __syncthreads();

    // ---------- phase 2: ks-major pipelined MFMA ----------
    const int w = tid >> 6, l = tid & 63;
    const int lcol = l & 15, g = l >> 4;
    const int col = w*16 + lcol;
    const u16* WB0 = WF0 + ((size_t)(e*8 + w)) * 20 * 512 + l*8;
    const u16* WB1 = WF1 + ((size_t)(e*8 + w)) * 16 * 512 + l*8;

    f32x4 accS = {0.f, 0.f, 0.f, 0.f};
    f32x4 accV[3];
#pragma unroll
    for (int m = 0; m < 3; ++m) accV[m] = accS;

    float4 scR0, scR1, scR2, scR3;

    short8 bS[2][5], bV[2][4];
#pragma unroll
    for (int p = 0; p < 5; ++p) bS[0][p] = *(const short8*)(WB0 + (p*4 + 0) * 512);
#pragma unroll
    for (int q = 0; q < 4; ++q) bV[0][q] = *(const short8*)(WB1 + (q*4 + 0) * 512);

#pragma unroll
    for (int ks = 0; ks < 4; ++ks) {
        const int cur = ks & 1, nxt = cur ^ 1;
        if (ks < 3) {
#pragma unroll
            for (int p = 0; p < 5; ++p) bS[nxt][p] = *(const short8*)(WB0 + (p*4 + ks + 1) * 512);
#pragma unroll
            for (int q = 0; q < 4; ++q) bV[nxt][q] = *(const short8*)(WB1 + (q*4 + ks + 1) * 512);
        }
        if (ks == 3 && n >= 0) {      // prefetch sc for the epilogue
            const float* sp = sc + (size_t)n * 512 + ch * 4;
            scR0 = *(const float4*)(sp);
            scR1 = *(const float4*)(sp + 128);
            scR2 = *(const float4*)(sp + 256);
            scR3 = *(const float4*)(sp + 384);
        }
        const int lp8 = (l ^ (ks << 1)) * 8;
#pragma unroll
        for (int p = 0; p < 5; ++p) {
            const short8 a = *(const short8*)&Afull[(p*4 + ks)*512 + lp8];
            accS = __builtin_amdgcn_mfma_f32_16x16x32_bf16(a, bS[cur][p], accS, 0, 0, 0);
        }
#pragma unroll
        for (int q = 0; q < 4; ++q)
#pragma unroll
            for (int m = 0; m < 3; ++m) {
                const short8 a = *(const short8*)&Afull[(20 + q*12 + m*4 + ks)*512 + lp8];
                accV[m] = __builtin_amdgcn_mfma_f32_16x16x32_bf16(a, bV[cur][q], accV[m], 0, 0, 0);
            }
    }

    // ---------- phase 3: stage in LDS, coalesced epilogue ----------
    __syncthreads();                   // everyone done reading A
    float* OutB = (float*)Afull;       // 16 x 516 floats
#pragma unroll
    for (int r = 0; r < 4; ++r) {
        const int nd = 4*g + r;
        OutB[nd*516 + col] = accS[r];
#pragma unroll
        for (int m = 0; m < 3; ++m)
            OutB[nd*516 + 128 + 3*col + m] = accV[m][r];
    }
    __syncthreads();

    if (n >= 0) {
        const size_t gb = (size_t)n * 512 + ch * 4;
        const float4 v0 = *(const float4*)&OutB[node*516 + ch*4];
        const float4 v1 = *(const float4*)&OutB[node*516 + ch*4 + 128];
        const float4 v2 = *(const float4*)&OutB[node*516 + ch*4 + 256];
        const float4 v3 = *(const float4*)&OutB[node*516 + ch*4 + 384];
        float4 o0, o1, o2, o3;
        o0.x=v0.x+scR0.x; o0.y=v0.y+scR0.y; o0.z=v0.z+scR0.z; o0.w=v0.w+scR0.w;
        o1.x=v1.x+scR1.x; o1.y=v1.y+scR1.y; o1.z=v1.z+scR1.z; o1.w=v1.w+scR1.w;
        o2.x=v2.x+scR2.x; o2.y=v2.y+scR2.y; o2.z=v2.z+scR2.z; o2.w=v2.w+scR2.w;
        o3.x=v3.x+scR3.x; o3.y=v3.y+scR3.y; o3.z=v3.z+scR3.z; o3.w=v3.w+scR3.w;
        *(float4*)(out + gb)       = o0;
        *(float4*)(out + gb + 128) = o1;
        *(float4*)(out + gb + 256) = o2;
        *(float4*)(out + gb + 384) = o3;
    }
}

extern "C" void kernel_launch(void* const* d_in, const int* in_sizes, int n_in,
                              void* d_out, int out_size, void* d_ws, size_t ws_size,
                              hipStream_t stream) {
    const float* feats = (const float*)d_in[0];
    const float* attrs = (const float*)d_in[1];
    const float* sc    = (const float*)d_in[2];
    const float* tp2   = (const float*)d_in[3];
    const float* tp3   = (const float*)d_in[4];
    const float* c00   = (const float*)d_in[5];
    const float* c01   = (const float*)d_in[6];
    const float* c10   = (const float*)d_in[7];
    const float* c11   = (const float*)d_in[8];
    const float* c20   = (const float*)d_in[9];
    const float* c21   = (const float*)d_in[10];
    const float* lin0  = (const float*)d_in[11];
    const float* lin1  = (const float*)d_in[12];
    float* out = (float*)d_out;

    char* ws = (char*)d_ws;
    u16* WF0   = (u16*)(ws);
    u16* WF1   = (u16*)(ws + WF0_BYTES);
    int* cnt   = (int*)(ws + CNT_OFF);
    int* lists = (int*)(ws + LIST_OFF);

    hipLaunchKernelGGL(zero_cnt_kernel, dim3(1), dim3(64), 0, stream, cnt);
    hipLaunchKernelGGL(prep_weights_kernel, dim3(E_*9), dim3(256), 0, stream,
                       tp2, tp3, c00, c10, c20, c01, c11, c21, lin0, lin1, WF0, WF1);
    hipLaunchKernelGGL(bucket_kernel, dim3((N_NODES + 255)/256), dim3(256), 0, stream,
                       attrs, cnt, lists);
    hipLaunchKernelGGL(main_kernel, dim3(NBLK_MAIN), dim3(512), 0, stream,
                       feats, sc, cnt, lists, WF0, WF1, out);
}